// Round 10
// baseline (48.718 us; speedup 1.0000x reference)
//
#include <hip/hip_runtime.h>
#include <math.h>

#define BATCH 128
#define CHN   128
#define HW    256            // 16*16
#define PLANE (CHN*HW)       // 32768
#define WELEM (CHN*CHN*9)    // 147456

using int4v  = __attribute__((ext_vector_type(4))) int;
using int16v = __attribute__((ext_vector_type(16))) int;
typedef unsigned int u32;

// async global->LDS, 16B per lane, dest = wave-uniform base + lane*16
__device__ __forceinline__ void gload16(const void* g, void* l) {
    __builtin_amdgcn_global_load_lds((const __attribute__((address_space(1))) u32*)g,
                                     (__attribute__((address_space(3))) u32*)l, 16, 0, 0);
}

// ---- ws layout (bytes) ----
// 0     : wmaxp (144 f)
// 2048  : s1part (512 x {sum,sumsq} = 4KB)
// 6144  : gS (128 i64)   7168 : gQ (128 i64)
// 8192  : wq1 i8 fragment order, 147456 B
// 155648: wq2 i8, 147456 B
// 303104: hbufT u8 codes1 [n][p][c0^swz(r(p))], 4 MB

__device__ __forceinline__ float wave_sum(float v) {
    #pragma unroll
    for (int off = 32; off; off >>= 1) v += __shfl_down(v, off, 64);
    return v;
}
__device__ __forceinline__ float wave_max(float v) {
    #pragma unroll
    for (int off = 32; off; off >>= 1) v = fmaxf(v, __shfl_down(v, off, 64));
    return v;
}

// ============ K1: stats1 partials (512 blocks) + wmax partials (144) ============
extern "C" __global__ void __launch_bounds__(256)
k_pre1(const float* __restrict__ x,
       const float* __restrict__ w1, const float* __restrict__ w2,
       float* __restrict__ s1part, float* __restrict__ wmaxp) {
    int b = blockIdx.x;
    int t = threadIdx.x;
    int lane = t & 63, wid = t >> 6;
    __shared__ float ls[8];

    if (b < 512) {
        int c = b >> 2, q = b & 3;
        const float* p = x + (size_t)(q * 32) * PLANE + c * HW + t;
        float s = 0.f, s2 = 0.f;
        #pragma unroll 16
        for (int n = 0; n < 32; ++n) {
            float v = p[n * PLANE];
            s += v; s2 += v * v;
        }
        s = wave_sum(s); s2 = wave_sum(s2);
        if (lane == 0) { ls[wid] = s; ls[4 + wid] = s2; }
        __syncthreads();
        if (t == 0) {
            s1part[b * 2]     = ls[0] + ls[1] + ls[2] + ls[3];
            s1part[b * 2 + 1] = ls[4] + ls[5] + ls[6] + ls[7];
        }
    } else {
        int i2 = b - 512;
        int y = (i2 >= 72) ? 1 : 0;
        int blk = i2 - y * 72;
        const float* w = y ? w2 : w1;
        int i = blk * 2048 + t;
        float m = 0.f;
        #pragma unroll
        for (int k = 0; k < 8; ++k)
            m = fmaxf(m, fabsf(tanhf(w[i + k * 256])));
        m = wave_max(m);
        if (lane == 0) ls[wid] = m;
        __syncthreads();
        if (t == 0)
            wmaxp[y * 72 + blk] = fmaxf(fmaxf(ls[0], ls[1]), fmaxf(ls[2], ls[3]));
    }
}

// ============ K2: actT1 (512 quarter-image blocks) + wquant (2x577 blocks) ============
extern "C" __global__ void __launch_bounds__(256)
k_mid(const float* __restrict__ x,
      const float* __restrict__ w1, const float* __restrict__ w2,
      const float* __restrict__ pat1, const float* __restrict__ pat2,
      const float* __restrict__ gamma1, const float* __restrict__ beta1,
      const float* __restrict__ s1part, const float* __restrict__ wmaxp,
      unsigned long long* __restrict__ gS, unsigned long long* __restrict__ gQ,
      signed char* __restrict__ wq1, signed char* __restrict__ wq2,
      unsigned char* __restrict__ hbufT) {
    int b = blockIdx.x;
    int t = threadIdx.x;

    if (b < 512) {
        // actT1 quarter-image: BN1 + quant + transpose, pre-swizzled codes
        __shared__ u32 tmp[16 * 129];
        __shared__ float2 tab[128];
        int n = b >> 2, quar = b & 3;
        if (t < 128) {
            float S  = s1part[(4 * t) * 2]     + s1part[(4 * t + 1) * 2]
                     + s1part[(4 * t + 2) * 2] + s1part[(4 * t + 3) * 2];
            float S2 = s1part[(4 * t) * 2 + 1] + s1part[(4 * t + 1) * 2 + 1]
                     + s1part[(4 * t + 2) * 2 + 1] + s1part[(4 * t + 3) * 2 + 1];
            float mean = S * (1.f / 32768.f);
            float var  = S2 * (1.f / 32768.f) - mean * mean;
            float istd = 1.0f / sqrtf(var + 1e-5f);
            float sc = istd * gamma1[t];
            float sh = beta1[t] - mean * sc;
            tab[t] = make_float2(sc, sh);
        }
        __syncthreads();

        const float* sp = x + (size_t)n * PLANE + quar * 64;
        #pragma unroll 8
        for (int j = 0; j < 8; ++j) {
            int id = j * 256 + t;            // c = id>>4 (0..127), p4 = id&15
            int cch = id >> 4, p4 = id & 15;
            float sc = tab[cch].x, sh = tab[cch].y;
            float4 v = *(const float4*)(sp + cch * HW + p4 * 4);
            unsigned q0 = (unsigned)(int)rintf(fminf(fmaxf(v.x * sc + sh, 0.f), 1.f) * 15.f);
            unsigned q1 = (unsigned)(int)rintf(fminf(fmaxf(v.y * sc + sh, 0.f), 1.f) * 15.f);
            unsigned q2 = (unsigned)(int)rintf(fminf(fmaxf(v.z * sc + sh, 0.f), 1.f) * 15.f);
            unsigned q3 = (unsigned)(int)rintf(fminf(fmaxf(v.w * sc + sh, 0.f), 1.f) * 15.f);
            tmp[p4 * 129 + cch] = q0 | (q1 << 8) | (q2 << 16) | (q3 << 24);
        }
        __syncthreads();

        if (t < 128) {
            unsigned char* dp = hbufT + (size_t)n * PLANE;
            int p4 = t >> 3;               // 0..15
            int c0 = (t & 7) * 16;
            u32 w[16];
            #pragma unroll
            for (int k = 0; k < 16; ++k) w[k] = tmp[p4 * 129 + c0 + k];
            #pragma unroll
            for (int pp = 0; pp < 4; ++pp) {
                int pg = quar * 64 + p4 * 4 + pp;
                int r = ((pg >> 4) + 1) * 18 + (pg & 15) + 1;
                int xr = (r & 7) << 4;
                int s = pp * 8;
                int4v o;
                o.x = (int)(((w[0] >> s) & 255u) | (((w[1] >> s) & 255u) << 8) |
                            (((w[2] >> s) & 255u) << 16) | (((w[3] >> s) & 255u) << 24));
                o.y = (int)(((w[4] >> s) & 255u) | (((w[5] >> s) & 255u) << 8) |
                            (((w[6] >> s) & 255u) << 16) | (((w[7] >> s) & 255u) << 24));
                o.z = (int)(((w[8] >> s) & 255u) | (((w[9] >> s) & 255u) << 8) |
                            (((w[10] >> s) & 255u) << 16) | (((w[11] >> s) & 255u) << 24));
                o.w = (int)(((w[12] >> s) & 255u) | (((w[13] >> s) & 255u) << 8) |
                            (((w[14] >> s) & 255u) << 16) | (((w[15] >> s) & 255u) << 24));
                *(int4v*)(dp + pg * 128 + (c0 ^ xr)) = o;
            }
        }
    } else {
        // weight quant: i2 in [0, 2*577)
        int i2 = b - 512;
        int y  = (i2 >= 577) ? 1 : 0;
        int xb = i2 - y * 577;

        if (xb == 576) {
            if (y == 0 && t < 128) { gS[t] = 0ull; gQ[t] = 0ull; }
            return;
        }
        const float* w   = y ? w2 : w1;
        const float* pat = y ? pat2 : pat1;
        signed char* wq  = y ? wq2 : wq1;

        __shared__ float lm[72];
        if (t < 72) lm[t] = wmaxp[y * 72 + t];
        __syncthreads();
        float M = lm[0];
        #pragma unroll
        for (int k = 1; k < 72; ++k) M = fmaxf(M, lm[k]);

        // byte i = ((ocq*2304 + tap*256 + q*64 + hq*32 + l31)*16 + j)
        int i = xb * 256 + t;
        int j = i & 15;
        int c = i >> 4;
        int ocq = c / 2304;
        int rem = c - ocq * 2304;
        int tap = rem >> 8;
        int r2  = rem & 255;
        int q   = r2 >> 6;
        int hq  = (r2 >> 5) & 1;
        int l31 = r2 & 31;
        int oc = ocq * 32 + l31;
        int ic = q * 32 + hq * 16 + j;
        float tv = tanhf(w[(oc * CHN + ic) * 9 + tap]);
        float tn = tv / (2.0f * M) + 0.5f;
        int mq = (int)rintf(tn * 15.f);
        mq = mq < 0 ? 0 : (mq > 15 ? 15 : mq);
        int qv = 2 * mq - 15;
        if (pat[tap] == 0.f) qv = 0;
        wq[i] = (signed char)qv;
    }
}

// ==================== shared conv helpers ====================
__device__ __forceinline__ void zero_halo(unsigned char* A, int t) {
    int4v z; z.x = 0; z.y = 0; z.z = 0; z.w = 0;
    for (int cidx = t; cidx < 544; cidx += 256) {
        int hrow = cidx >> 3, ch = cidx & 7;
        int r;
        if (hrow < 18) r = hrow;
        else if (hrow < 36) r = 306 + (hrow - 18);
        else { int h2 = hrow - 36; r = (1 + (h2 & 15)) * 18 + ((h2 >> 4) ? 17 : 0); }
        *(int4v*)(A + r * 128 + ch * 16) = z;
    }
}
__device__ __forceinline__ void stage_act(const unsigned char* ap, unsigned char* A,
                                          int wid, int lane) {
    #pragma unroll
    for (int j = 0; j < 8; ++j) {
        int p0w = j * 32 + wid * 8;
        int r0 = ((p0w >> 4) + 1) * 18 + (p0w & 15) + 1;
        gload16(ap + p0w * 128 + (lane << 4), A + r0 * 128);
    }
}
// one K-half (q pair) of a 32-oc weight tile: 18KB
__device__ __forceinline__ void stage_Whalf(const unsigned char* wsrc, unsigned char* Wh,
                                            int half, int wid, int lane) {
    for (int it = wid; it < 18; it += 4)
        gload16(wsrc + (it >> 1) * 4096 + half * 2048 + (it & 1) * 1024 + (lane << 4),
                Wh + (it >> 1) * 2048 + (it & 1) * 1024);
}
__device__ __forceinline__ void mfma_half(const unsigned char* A, const unsigned char* Wh,
                                          const bool pf[9], int qbase,
                                          int h0, int w0c, int h1, int w1c,
                                          int cbase, int lane,
                                          int16v& acc0, int16v& acc1) {
    #pragma unroll
    for (int tap = 0; tap < 9; ++tap) {
        if (pf[tap]) {
            int dy = tap / 3, dx = tap % 3;
            int r0 = (h0 + dy) * 18 + (w0c + dx);
            int r1 = (h1 + dy) * 18 + (w1c + dx);
            int b0base = r0 * 128 + (cbase ^ ((r0 & 7) << 4));
            int b1base = r1 * 128 + (cbase ^ ((r1 & 7) << 4));
            const unsigned char* wt = Wh + tap * 2048 + (lane << 4);
            #pragma unroll
            for (int qq = 0; qq < 2; ++qq) {
                int q = qbase + qq;
                int4v a0 = *(const int4v*)(wt + qq * 1024);
                int4v b0 = *(const int4v*)(A + (b0base ^ (q << 5)));
                int4v b1 = *(const int4v*)(A + (b1base ^ (q << 5)));
                acc0 = __builtin_amdgcn_mfma_i32_32x32x32_i8(a0, b0, acc0, 0, 0, 0);
                acc1 = __builtin_amdgcn_mfma_i32_32x32x32_i8(a0, b1, acc1, 0, 0, 0);
            }
        }
    }
}
// XCD-aware decode: same-image blocks share L%8 (one XCD under round-robin)
__device__ __forceinline__ void decode_swz(int L, int& n, int& ocq) {
    int r8 = L & 7, k = L >> 3;
    ocq = k & 3;
    n = r8 + 8 * (k >> 2);
}

#define ZERO_ACC() { _Pragma("unroll") for (int e = 0; e < 16; ++e) { acc0[e] = 0; acc1[e] = 0; } }

// ============ K3: conv1 + exact BN2 stats, NO output write (pipelined W halves) ============
extern "C" __global__ void __launch_bounds__(256, 2)
k_conv1s(const unsigned char* __restrict__ actT,
         const signed char*  __restrict__ wq,
         const float* __restrict__ pat,
         unsigned long long* __restrict__ gS, unsigned long long* __restrict__ gQ) {
    int n, ocq;
    decode_swz(blockIdx.x, n, ocq);
    int t = threadIdx.x;
    int lane = t & 63, wid = t >> 6;
    int l31 = lane & 31, hq = lane >> 5;

    __shared__ __align__(16) unsigned char lds[41472 + 2 * 18432];
    unsigned char* A  = lds;
    unsigned char* B0 = lds + 41472;
    unsigned char* B1 = lds + 41472 + 18432;
    const unsigned char* wsrc = (const unsigned char*)wq + (size_t)ocq * 36864;

    zero_halo(A, t);
    stage_act(actT + (size_t)n * PLANE, A, wid, lane);
    stage_Whalf(wsrc, B0, 0, wid, lane);

    bool pf[9];
    #pragma unroll
    for (int j = 0; j < 9; ++j) pf[j] = (pat[j] != 0.f);

    __syncthreads();

    int16v acc0, acc1;
    ZERO_ACC();

    int p0 = wid * 64 + l31;
    int h0 = p0 >> 4, w0c = p0 & 15;
    int p1 = p0 + 32;
    int h1 = p1 >> 4, w1c = p1 & 15;
    int cbase = hq * 16;

    stage_Whalf(wsrc, B1, 1, wid, lane);                       // overlap with h0 MFMAs
    mfma_half(A, B0, pf, 0, h0, w0c, h1, w1c, cbase, lane, acc0, acc1);
    __syncthreads();
    mfma_half(A, B1, pf, 2, h0, w0c, h1, w1c, cbase, lane, acc0, acc1);

    __syncthreads();      // done with LDS; reuse for stats
    int*       lsm = (int*)lds;
    long long* lq  = (long long*)(lds + 512);
    #pragma unroll
    for (int e = 0; e < 16; ++e) {
        int a0 = acc0[e], a1 = acc1[e];
        int s = a0 + a1;
        long long qq = (long long)a0 * a0 + (long long)a1 * a1;
        #pragma unroll
        for (int off = 1; off < 32; off <<= 1) {
            s  += __shfl_xor(s, off, 64);
            qq += __shfl_xor(qq, off, 64);
        }
        if (l31 == 0) {
            int ch = (e & 3) + 8 * (e >> 2) + 4 * hq;
            lsm[wid * 32 + ch] = s;
            lq [wid * 32 + ch] = qq;
        }
    }
    __syncthreads();
    if (t < 32) {
        long long S = 0, Q = 0;
        #pragma unroll
        for (int w = 0; w < 4; ++w) { S += lsm[w * 32 + t]; Q += lq[w * 32 + t]; }
        atomicAdd(gS + ocq * 32 + t, (unsigned long long)S);
        atomicAdd(gQ + ocq * 32 + t, (unsigned long long)Q);
    }
}

// ============ K4: recompute conv1 (all 128 ch, pipelined) -> quant in-reg -> conv2 ============
extern "C" __global__ void __launch_bounds__(256, 2)
k_conv2(const unsigned char* __restrict__ hb,     // codes1
        const signed char* __restrict__ wq1, const signed char* __restrict__ wq2,
        const float* __restrict__ pat1, const float* __restrict__ pat2,
        const float* __restrict__ gamma2, const float* __restrict__ beta2,
        const unsigned long long* __restrict__ gS, const unsigned long long* __restrict__ gQ,
        const float* __restrict__ x, float* __restrict__ out) {
    int n, ocq;
    decode_swz(blockIdx.x, n, ocq);
    int t = threadIdx.x;
    int lane = t & 63, wid = t >> 6;
    int l31 = lane & 31, hq = lane >> 5;

    __shared__ __align__(16) unsigned char lds[41472 + 2 * 18432];
    __shared__ float2 tab[128];
    unsigned char* A  = lds;
    unsigned char* B0 = lds + 41472;
    unsigned char* B1 = lds + 41472 + 18432;

    // BN2 scale/shift for ALL channels (gS/gQ final after k_conv1s)
    if (t < 128) {
        long long S = (long long)gS[t];
        long long Q = (long long)gQ[t];
        double mean = (double)S * (1.0 / (32768.0 * 225.0));
        double ex2  = (double)Q * (1.0 / (32768.0 * 225.0 * 225.0));
        double var  = ex2 - mean * mean;
        float istd = (float)(1.0 / sqrt(var + 1e-5));
        float sc = istd * gamma2[t];
        float sh = beta2[t] - (float)mean * sc;
        tab[t] = make_float2(sc, sh);
    }

    zero_halo(A, t);
    stage_act(hb + (size_t)n * PLANE, A, wid, lane);    // codes1
    const unsigned char* w1b = (const unsigned char*)wq1;
    const unsigned char* w2b = (const unsigned char*)wq2 + (size_t)ocq * 36864;
    stage_Whalf(w1b, B0, 0, wid, lane);                 // tile0 half0

    bool pf1[9], pf2[9];
    #pragma unroll
    for (int j = 0; j < 9; ++j) { pf1[j] = (pat1[j] != 0.f); pf2[j] = (pat2[j] != 0.f); }

    int p0 = wid * 64 + l31;
    int h0 = p0 >> 4, w0c = p0 & 15;
    int p1 = p0 + 32;
    int h1 = p1 >> 4, w1c = p1 & 15;
    int cbase = hq * 16;

    __syncthreads();

    int4v cod[4][2];
    int16v acc0, acc1;

    // quantize acc pair -> packed codes2 for tile tt (register-only; tab is read-only LDS)
    #define QUANT(tt)                                                                   \
    {                                                                                   \
        _Pragma("unroll")                                                               \
        for (int h2 = 0; h2 < 2; ++h2) {                                                \
            const int16v& ac = h2 ? acc1 : acc0;                                        \
            u32 wrd[4];                                                                 \
            _Pragma("unroll")                                                           \
            for (int k = 0; k < 4; ++k) {                                               \
                u32 pk = 0;                                                             \
                _Pragma("unroll")                                                       \
                for (int e2 = 0; e2 < 4; ++e2) {                                        \
                    int e = 4 * k + e2;                                                 \
                    int row = (e & 3) + 8 * k + 4 * hq;                                 \
                    float2 ss = tab[(tt) * 32 + row];                                   \
                    float v = (float)ac[e] * (1.f / 225.f);                             \
                    u32 q = (u32)(int)rintf(fminf(fmaxf(v * ss.x + ss.y, 0.f), 1.f) * 15.f); \
                    pk |= q << (8 * e2);                                                \
                }                                                                       \
                wrd[k] = pk;                                                            \
            }                                                                           \
            u32 prt[4];                                                                 \
            _Pragma("unroll")                                                           \
            for (int k = 0; k < 4; ++k) prt[k] = __shfl_xor(wrd[k], 32, 64);            \
            int4v o;                                                                    \
            if (hq == 0) { o.x = (int)wrd[0]; o.y = (int)prt[0]; o.z = (int)wrd[1]; o.w = (int)prt[1]; } \
            else         { o.x = (int)prt[2]; o.y = (int)wrd[2]; o.z = (int)prt[3]; o.w = (int)wrd[3]; } \
            cod[tt][h2] = o;                                                            \
        }                                                                               \
    }

    // ---- conv1 recompute, 4 tiles x 2 half-K phases, W double-buffered ----
    // tile 0
    ZERO_ACC();
    stage_Whalf(w1b, B1, 1, wid, lane);
    mfma_half(A, B0, pf1, 0, h0, w0c, h1, w1c, cbase, lane, acc0, acc1);
    __syncthreads();
    stage_Whalf(w1b + 36864, B0, 0, wid, lane);
    mfma_half(A, B1, pf1, 2, h0, w0c, h1, w1c, cbase, lane, acc0, acc1);
    QUANT(0);
    __syncthreads();
    // tile 1
    ZERO_ACC();
    stage_Whalf(w1b + 36864, B1, 1, wid, lane);
    mfma_half(A, B0, pf1, 0, h0, w0c, h1, w1c, cbase, lane, acc0, acc1);
    __syncthreads();
    stage_Whalf(w1b + 2 * 36864, B0, 0, wid, lane);
    mfma_half(A, B1, pf1, 2, h0, w0c, h1, w1c, cbase, lane, acc0, acc1);
    QUANT(1);
    __syncthreads();
    // tile 2
    ZERO_ACC();
    stage_Whalf(w1b + 2 * 36864, B1, 1, wid, lane);
    mfma_half(A, B0, pf1, 0, h0, w0c, h1, w1c, cbase, lane, acc0, acc1);
    __syncthreads();
    stage_Whalf(w1b + 3 * 36864, B0, 0, wid, lane);
    mfma_half(A, B1, pf1, 2, h0, w0c, h1, w1c, cbase, lane, acc0, acc1);
    QUANT(2);
    __syncthreads();
    // tile 3
    ZERO_ACC();
    stage_Whalf(w1b + 3 * 36864, B1, 1, wid, lane);
    mfma_half(A, B0, pf1, 0, h0, w0c, h1, w1c, cbase, lane, acc0, acc1);
    __syncthreads();
    stage_Whalf(w2b, B0, 0, wid, lane);              // conv2 weights half0
    mfma_half(A, B1, pf1, 2, h0, w0c, h1, w1c, cbase, lane, acc0, acc1);
    QUANT(3);
    __syncthreads();

    // ---- rewrite A with codes2 (interior rows only; halo stays zero) ----
    #pragma unroll
    for (int tt = 0; tt < 4; ++tt) {
        #pragma unroll
        for (int h2 = 0; h2 < 2; ++h2) {
            int p = h2 ? p1 : p0;
            int c0 = tt * 32 + (hq ? 16 : 0);
            int r = ((p >> 4) + 1) * 18 + (p & 15) + 1;
            int xr = (r & 7) << 4;
            *(int4v*)(A + r * 128 + (c0 ^ xr)) = cod[tt][h2];
        }
    }
    __syncthreads();

    // ---- conv2 ----
    ZERO_ACC();
    stage_Whalf(w2b, B1, 1, wid, lane);
    mfma_half(A, B0, pf2, 0, h0, w0c, h1, w1c, cbase, lane, acc0, acc1);
    __syncthreads();
    mfma_half(A, B1, pf2, 2, h0, w0c, h1, w1c, cbase, lane, acc0, acc1);

    // ---- epilogue: out = conv2/225 + x ----
    float* ob = out + ((size_t)n * CHN + ocq * 32) * HW;
    const float* xb = x + ((size_t)n * CHN + ocq * 32) * HW;
    #pragma unroll
    for (int e = 0; e < 16; ++e) {
        int row = (e & 3) + 8 * (e >> 2) + 4 * hq;
        int idx0 = row * HW + wid * 64 + l31;
        ob[idx0]      = (float)acc0[e] * (1.f / 225.f) + xb[idx0];
        ob[idx0 + 32] = (float)acc1[e] * (1.f / 225.f) + xb[idx0 + 32];
    }
    #undef QUANT
}

extern "C" void kernel_launch(void* const* d_in, const int* in_sizes, int n_in,
                              void* d_out, int out_size, void* d_ws, size_t ws_size,
                              hipStream_t stream) {
    const float* x      = (const float*)d_in[0];
    const float* gamma1 = (const float*)d_in[1];
    const float* beta1  = (const float*)d_in[2];
    const float* gamma2 = (const float*)d_in[3];
    const float* beta2  = (const float*)d_in[4];
    const float* w1     = (const float*)d_in[5];
    const float* w2     = (const float*)d_in[6];
    const float* pat1   = (const float*)d_in[7];
    const float* pat2   = (const float*)d_in[8];
    float* out = (float*)d_out;

    char* ws = (char*)d_ws;
    float* wmaxp     = (float*)(ws + 0);
    float* s1part    = (float*)(ws + 2048);
    unsigned long long* gS = (unsigned long long*)(ws + 6144);
    unsigned long long* gQ = (unsigned long long*)(ws + 7168);
    signed char* wq1 = (signed char*)(ws + 8192);
    signed char* wq2 = (signed char*)(ws + 155648);
    unsigned char* hbufT = (unsigned char*)(ws + 303104);

    k_pre1<<<656, 256, 0, stream>>>(x, w1, w2, s1part, wmaxp);
    k_mid<<<512 + 2 * 577, 256, 0, stream>>>(x, w1, w2, pat1, pat2, gamma1, beta1,
                                             s1part, wmaxp, gS, gQ, wq1, wq2, hbufT);
    k_conv1s<<<512, 256, 0, stream>>>(hbufT, wq1, pat1, gS, gQ);
    k_conv2<<<512, 256, 0, stream>>>(hbufT, wq1, wq2, pat1, pat2,
                                     gamma2, beta2, gS, gQ, x, out);
}

// Round 11
// 45.911 us; speedup vs baseline: 1.0611x; 1.0611x over previous
//
#include <hip/hip_runtime.h>
#include <math.h>

#define BATCH 128
#define CHN   128
#define HW    256            // 16*16
#define PLANE (CHN*HW)       // 32768
#define WELEM (CHN*CHN*9)    // 147456

using int4v  = __attribute__((ext_vector_type(4))) int;
using int16v = __attribute__((ext_vector_type(16))) int;
typedef unsigned int u32;

// async global->LDS, 16B per lane, dest = wave-uniform base + lane*16
__device__ __forceinline__ void gload16(const void* g, void* l) {
    __builtin_amdgcn_global_load_lds((const __attribute__((address_space(1))) u32*)g,
                                     (__attribute__((address_space(3))) u32*)l, 16, 0, 0);
}

// ---- ws layout (bytes) ----
// 0     : wmaxp (144 f)
// 2048  : s1part (512 x {sum,sumsq} = 4KB)
// 6144  : gS shadows [8][128] i64 = 8KB
// 14336 : gQ shadows [8][128] i64 = 8KB
// 22528 : wq1 i8 fragment order, 147456 B
// 169984: wq2 i8, 147456 B
// 317440: hbufT u8 codes1 [n][p][c0^swz(r(p))], 4 MB

__device__ __forceinline__ float wave_sum(float v) {
    #pragma unroll
    for (int off = 32; off; off >>= 1) v += __shfl_down(v, off, 64);
    return v;
}
__device__ __forceinline__ float wave_max(float v) {
    #pragma unroll
    for (int off = 32; off; off >>= 1) v = fmaxf(v, __shfl_down(v, off, 64));
    return v;
}

// ============ K1: stats1 partials (512 blocks) + wmax partials (144) ============
extern "C" __global__ void __launch_bounds__(256)
k_pre1(const float* __restrict__ x,
       const float* __restrict__ w1, const float* __restrict__ w2,
       float* __restrict__ s1part, float* __restrict__ wmaxp) {
    int b = blockIdx.x;
    int t = threadIdx.x;
    int lane = t & 63, wid = t >> 6;
    __shared__ float ls[8];

    if (b < 512) {
        int c = b >> 2, q = b & 3;
        const float* p = x + (size_t)(q * 32) * PLANE + c * HW + t;
        float s = 0.f, s2 = 0.f;
        #pragma unroll 8
        for (int n = 0; n < 32; ++n) {
            float v = p[n * PLANE];
            s += v; s2 += v * v;
        }
        s = wave_sum(s); s2 = wave_sum(s2);
        if (lane == 0) { ls[wid] = s; ls[4 + wid] = s2; }
        __syncthreads();
        if (t == 0) {
            s1part[b * 2]     = ls[0] + ls[1] + ls[2] + ls[3];
            s1part[b * 2 + 1] = ls[4] + ls[5] + ls[6] + ls[7];
        }
    } else {
        int i2 = b - 512;
        int y = (i2 >= 72) ? 1 : 0;
        int blk = i2 - y * 72;
        const float* w = y ? w2 : w1;
        int i = blk * 2048 + t;
        float m = 0.f;
        #pragma unroll
        for (int k = 0; k < 8; ++k)
            m = fmaxf(m, fabsf(tanhf(w[i + k * 256])));
        m = wave_max(m);
        if (lane == 0) ls[wid] = m;
        __syncthreads();
        if (t == 0)
            wmaxp[y * 72 + blk] = fmaxf(fmaxf(ls[0], ls[1]), fmaxf(ls[2], ls[3]));
    }
}

// ============ K2: actT1 (256 half-image blocks) + wquant (2x577 blocks) ============
extern "C" __global__ void __launch_bounds__(256)
k_mid(const float* __restrict__ x,
      const float* __restrict__ w1, const float* __restrict__ w2,
      const float* __restrict__ pat1, const float* __restrict__ pat2,
      const float* __restrict__ gamma1, const float* __restrict__ beta1,
      const float* __restrict__ s1part, const float* __restrict__ wmaxp,
      unsigned long long* __restrict__ gS, unsigned long long* __restrict__ gQ,
      signed char* __restrict__ wq1, signed char* __restrict__ wq2,
      unsigned char* __restrict__ hbufT) {
    int b = blockIdx.x;
    int t = threadIdx.x;

    if (b < 256) {
        // actT1: BN1 + quant + transpose, pre-swizzled codes
        __shared__ u32 tmp[32 * 129];
        __shared__ float2 tab[128];
        int n = b >> 1, half = b & 1;
        if (t < 128) {
            float S  = s1part[(4 * t) * 2]     + s1part[(4 * t + 1) * 2]
                     + s1part[(4 * t + 2) * 2] + s1part[(4 * t + 3) * 2];
            float S2 = s1part[(4 * t) * 2 + 1] + s1part[(4 * t + 1) * 2 + 1]
                     + s1part[(4 * t + 2) * 2 + 1] + s1part[(4 * t + 3) * 2 + 1];
            float mean = S * (1.f / 32768.f);
            float var  = S2 * (1.f / 32768.f) - mean * mean;
            float istd = 1.0f / sqrtf(var + 1e-5f);
            float sc = istd * gamma1[t];
            float sh = beta1[t] - mean * sc;
            tab[t] = make_float2(sc, sh);
        }
        __syncthreads();

        const float* sp = x + (size_t)n * PLANE + half * 128;
        #pragma unroll 8
        for (int j = 0; j < 16; ++j) {
            int id = j * 256 + t;            // cch = id>>5, p4 = id&31
            int cch = id >> 5, p4 = id & 31;
            float sc = tab[cch].x, sh = tab[cch].y;
            float4 v = *(const float4*)(sp + cch * HW + p4 * 4);
            unsigned q0 = (unsigned)(int)rintf(fminf(fmaxf(v.x * sc + sh, 0.f), 1.f) * 15.f);
            unsigned q1 = (unsigned)(int)rintf(fminf(fmaxf(v.y * sc + sh, 0.f), 1.f) * 15.f);
            unsigned q2 = (unsigned)(int)rintf(fminf(fmaxf(v.z * sc + sh, 0.f), 1.f) * 15.f);
            unsigned q3 = (unsigned)(int)rintf(fminf(fmaxf(v.w * sc + sh, 0.f), 1.f) * 15.f);
            tmp[p4 * 129 + cch] = q0 | (q1 << 8) | (q2 << 16) | (q3 << 24);
        }
        __syncthreads();

        unsigned char* dp = hbufT + (size_t)n * PLANE + half * 128 * CHN;
        int p4 = t >> 3;
        int c0 = (t & 7) * 16;
        u32 w[16];
        #pragma unroll
        for (int k = 0; k < 16; ++k) w[k] = tmp[p4 * 129 + c0 + k];
        #pragma unroll
        for (int pp = 0; pp < 4; ++pp) {
            int p = p4 * 4 + pp;
            int pg = half * 128 + p;
            int r = ((pg >> 4) + 1) * 18 + (pg & 15) + 1;
            int xr = (r & 7) << 4;
            int s = pp * 8;
            int4v o;
            o.x = (int)(((w[0] >> s) & 255u) | (((w[1] >> s) & 255u) << 8) |
                        (((w[2] >> s) & 255u) << 16) | (((w[3] >> s) & 255u) << 24));
            o.y = (int)(((w[4] >> s) & 255u) | (((w[5] >> s) & 255u) << 8) |
                        (((w[6] >> s) & 255u) << 16) | (((w[7] >> s) & 255u) << 24));
            o.z = (int)(((w[8] >> s) & 255u) | (((w[9] >> s) & 255u) << 8) |
                        (((w[10] >> s) & 255u) << 16) | (((w[11] >> s) & 255u) << 24));
            o.w = (int)(((w[12] >> s) & 255u) | (((w[13] >> s) & 255u) << 8) |
                        (((w[14] >> s) & 255u) << 16) | (((w[15] >> s) & 255u) << 24));
            *(int4v*)(dp + p * 128 + (c0 ^ xr)) = o;
        }
    } else {
        // weight quant: i2 in [0, 2*577)
        int i2 = b - 256;
        int y  = (i2 >= 577) ? 1 : 0;
        int xb = i2 - y * 577;

        if (xb == 576) {
            if (y == 0) {
                for (int k = t; k < 1024; k += 256) { gS[k] = 0ull; gQ[k] = 0ull; }
            }
            return;
        }
        const float* w   = y ? w2 : w1;
        const float* pat = y ? pat2 : pat1;
        signed char* wq  = y ? wq2 : wq1;

        __shared__ float lm[72];
        if (t < 72) lm[t] = wmaxp[y * 72 + t];
        __syncthreads();
        float M = lm[0];
        #pragma unroll
        for (int k = 1; k < 72; ++k) M = fmaxf(M, lm[k]);

        // byte i = ((ocq*2304 + tap*256 + q*64 + hq*32 + l31)*16 + j)
        int i = xb * 256 + t;
        int j = i & 15;
        int c = i >> 4;
        int ocq = c / 2304;
        int rem = c - ocq * 2304;
        int tap = rem >> 8;
        int r2  = rem & 255;
        int q   = r2 >> 6;
        int hq  = (r2 >> 5) & 1;
        int l31 = r2 & 31;
        int oc = ocq * 32 + l31;
        int ic = q * 32 + hq * 16 + j;
        float tv = tanhf(w[(oc * CHN + ic) * 9 + tap]);
        float tn = tv / (2.0f * M) + 0.5f;
        int mq = (int)rintf(tn * 15.f);
        mq = mq < 0 ? 0 : (mq > 15 ? 15 : mq);
        int qv = 2 * mq - 15;
        if (pat[tap] == 0.f) qv = 0;
        wq[i] = (signed char)qv;
    }
}

// ==================== shared conv helpers ====================
__device__ __forceinline__ void zero_halo(unsigned char* A, int t) {
    int4v z; z.x = 0; z.y = 0; z.z = 0; z.w = 0;
    for (int cidx = t; cidx < 544; cidx += 256) {
        int hrow = cidx >> 3, ch = cidx & 7;
        int r;
        if (hrow < 18) r = hrow;
        else if (hrow < 36) r = 306 + (hrow - 18);
        else { int h2 = hrow - 36; r = (1 + (h2 & 15)) * 18 + ((h2 >> 4) ? 17 : 0); }
        *(int4v*)(A + r * 128 + ch * 16) = z;
    }
}
__device__ __forceinline__ void stage_act(const unsigned char* ap, unsigned char* A,
                                          int wid, int lane) {
    #pragma unroll
    for (int j = 0; j < 8; ++j) {
        int p0w = j * 32 + wid * 8;
        int r0 = ((p0w >> 4) + 1) * 18 + (p0w & 15) + 1;
        gload16(ap + p0w * 128 + (lane << 4), A + r0 * 128);
    }
}
__device__ __forceinline__ void stage_W(const unsigned char* wsrc, unsigned char* W,
                                        int wid, int lane) {
    #pragma unroll
    for (int it = 0; it < 9; ++it)
        gload16(wsrc + it * 4096 + wid * 1024 + (lane << 4),
                W + it * 4096 + wid * 1024);
}
__device__ __forceinline__ void mfma_full(const unsigned char* A, const unsigned char* W,
                                          const bool pf[9],
                                          int h0, int w0c, int h1, int w1c,
                                          int cbase, int lane,
                                          int16v& acc0, int16v& acc1) {
    #pragma unroll
    for (int tap = 0; tap < 9; ++tap) {
        if (pf[tap]) {
            int dy = tap / 3, dx = tap % 3;
            int r0 = (h0 + dy) * 18 + (w0c + dx);
            int r1 = (h1 + dy) * 18 + (w1c + dx);
            int b0base = r0 * 128 + (cbase ^ ((r0 & 7) << 4));
            int b1base = r1 * 128 + (cbase ^ ((r1 & 7) << 4));
            const unsigned char* wt = W + tap * 4096 + (lane << 4);
            #pragma unroll
            for (int q = 0; q < 4; ++q) {
                int4v a0 = *(const int4v*)(wt + q * 1024);
                int4v b0 = *(const int4v*)(A + (b0base ^ (q << 5)));
                int4v b1 = *(const int4v*)(A + (b1base ^ (q << 5)));
                acc0 = __builtin_amdgcn_mfma_i32_32x32x32_i8(a0, b0, acc0, 0, 0, 0);
                acc1 = __builtin_amdgcn_mfma_i32_32x32x32_i8(a0, b1, acc1, 0, 0, 0);
            }
        }
    }
}

// ============ K3: conv1 + exact BN2 stats (XCD-local shadows), NO output write ============
extern "C" __global__ void __launch_bounds__(256, 2)
k_conv1s(const unsigned char* __restrict__ actT,
         const signed char*  __restrict__ wq,
         const float* __restrict__ pat,
         unsigned long long* __restrict__ gS, unsigned long long* __restrict__ gQ) {
    int n = blockIdx.x, ocq = blockIdx.y;
    int t = threadIdx.x;
    int lane = t & 63, wid = t >> 6;
    int l31 = lane & 31, hq = lane >> 5;

    __shared__ __align__(16) unsigned char lds[41472 + 36864];
    unsigned char* A = lds;
    unsigned char* W = lds + 41472;

    zero_halo(A, t);
    stage_W((const unsigned char*)wq + (size_t)ocq * 36864, W, wid, lane);
    stage_act(actT + (size_t)n * PLANE, A, wid, lane);

    bool pf[9];
    #pragma unroll
    for (int j = 0; j < 9; ++j) pf[j] = (pat[j] != 0.f);

    __syncthreads();

    int16v acc0, acc1;
    #pragma unroll
    for (int e = 0; e < 16; ++e) { acc0[e] = 0; acc1[e] = 0; }

    int p0 = wid * 64 + l31;
    int h0 = p0 >> 4, w0c = p0 & 15;
    int p1 = p0 + 32;
    int h1 = p1 >> 4, w1c = p1 & 15;
    int cbase = hq * 16;

    mfma_full(A, W, pf, h0, w0c, h1, w1c, cbase, lane, acc0, acc1);

    __syncthreads();      // done with LDS; reuse for stats
    int*       lsm = (int*)lds;
    long long* lq  = (long long*)(lds + 512);
    #pragma unroll
    for (int e = 0; e < 16; ++e) {
        int a0 = acc0[e], a1 = acc1[e];
        int s = a0 + a1;
        long long qq = (long long)a0 * a0 + (long long)a1 * a1;
        #pragma unroll
        for (int off = 1; off < 32; off <<= 1) {
            s  += __shfl_xor(s, off, 64);
            qq += __shfl_xor(qq, off, 64);
        }
        if (l31 == 0) {
            int ch = (e & 3) + 8 * (e >> 2) + 4 * hq;
            lsm[wid * 32 + ch] = s;
            lq [wid * 32 + ch] = qq;
        }
    }
    __syncthreads();
    if (t < 32) {
        long long S = 0, Q = 0;
        #pragma unroll
        for (int w = 0; w < 4; ++w) { S += lsm[w * 32 + t]; Q += lq[w * 32 + t]; }
        // XCD-local shadow: block (n,ocq) sits on XCD n%8 (128 % 8 == 0)
        int sh = (n & 7) * 128 + ocq * 32 + t;
        atomicAdd(gS + sh, (unsigned long long)S);
        atomicAdd(gQ + sh, (unsigned long long)Q);
    }
}

// ============ K4: recompute conv1 (all 128 ch) -> quant in-reg -> codes2 in LDS -> conv2 ============
extern "C" __global__ void __launch_bounds__(256, 2)
k_conv2(const unsigned char* __restrict__ hb,     // codes1
        const signed char* __restrict__ wq1, const signed char* __restrict__ wq2,
        const float* __restrict__ pat1, const float* __restrict__ pat2,
        const float* __restrict__ gamma2, const float* __restrict__ beta2,
        const unsigned long long* __restrict__ gS, const unsigned long long* __restrict__ gQ,
        const float* __restrict__ x, float* __restrict__ out) {
    int n = blockIdx.x, ocq = blockIdx.y;
    int t = threadIdx.x;
    int lane = t & 63, wid = t >> 6;
    int l31 = lane & 31, hq = lane >> 5;

    __shared__ __align__(16) unsigned char lds[41472 + 36864];
    __shared__ float2 tab[128];
    unsigned char* A = lds;
    unsigned char* W = lds + 41472;

    // BN2 scale/shift for ALL channels: sum the 8 XCD shadows (exact i64)
    if (t < 128) {
        long long S = 0, Q = 0;
        #pragma unroll
        for (int r = 0; r < 8; ++r) {
            S += (long long)gS[r * 128 + t];
            Q += (long long)gQ[r * 128 + t];
        }
        double mean = (double)S * (1.0 / (32768.0 * 225.0));
        double ex2  = (double)Q * (1.0 / (32768.0 * 225.0 * 225.0));
        double var  = ex2 - mean * mean;
        float istd = (float)(1.0 / sqrt(var + 1e-5));
        float sc = istd * gamma2[t];
        float sh = beta2[t] - (float)mean * sc;
        tab[t] = make_float2(sc, sh);
    }

    zero_halo(A, t);
    stage_act(hb + (size_t)n * PLANE, A, wid, lane);    // codes1

    bool pf1[9], pf2[9];
    #pragma unroll
    for (int j = 0; j < 9; ++j) { pf1[j] = (pat1[j] != 0.f); pf2[j] = (pat2[j] != 0.f); }

    int p0 = wid * 64 + l31;
    int h0 = p0 >> 4, w0c = p0 & 15;
    int p1 = p0 + 32;
    int h1 = p1 >> 4, w1c = p1 & 15;
    int cbase = hq * 16;

    int4v cod[4][2];
    int16v acc0, acc1;

    // ---- recompute conv1 for all 4 oc-tiles; quantize each to codes2 in registers ----
    #pragma unroll
    for (int tt = 0; tt < 4; ++tt) {
        stage_W((const unsigned char*)wq1 + (size_t)tt * 36864, W, wid, lane);
        __syncthreads();

        #pragma unroll
        for (int e = 0; e < 16; ++e) { acc0[e] = 0; acc1[e] = 0; }
        mfma_full(A, W, pf1, h0, w0c, h1, w1c, cbase, lane, acc0, acc1);

        #pragma unroll
        for (int h2 = 0; h2 < 2; ++h2) {
            const int16v& ac = h2 ? acc1 : acc0;
            u32 wrd[4];
            #pragma unroll
            for (int k = 0; k < 4; ++k) {
                u32 pk = 0;
                #pragma unroll
                for (int e2 = 0; e2 < 4; ++e2) {
                    int e = 4 * k + e2;
                    int row = (e & 3) + 8 * k + 4 * hq;
                    float2 ss = tab[tt * 32 + row];
                    float v = (float)ac[e] * (1.f / 225.f);
                    u32 q = (u32)(int)rintf(fminf(fmaxf(v * ss.x + ss.y, 0.f), 1.f) * 15.f);
                    pk |= q << (8 * e2);
                }
                wrd[k] = pk;
            }
            u32 prt[4];
            #pragma unroll
            for (int k = 0; k < 4; ++k) prt[k] = __shfl_xor(wrd[k], 32, 64);
            int4v o;
            if (hq == 0) { o.x = (int)wrd[0]; o.y = (int)prt[0]; o.z = (int)wrd[1]; o.w = (int)prt[1]; }
            else         { o.x = (int)prt[2]; o.y = (int)wrd[2]; o.z = (int)prt[3]; o.w = (int)wrd[3]; }
            cod[tt][h2] = o;
        }
        __syncthreads();   // all waves done reading A/W before next W staging / A rewrite
    }

    // ---- rewrite A with codes2 (interior rows only; halo stays zero) ----
    #pragma unroll
    for (int tt = 0; tt < 4; ++tt) {
        #pragma unroll
        for (int h2 = 0; h2 < 2; ++h2) {
            int p = h2 ? p1 : p0;
            int c0 = tt * 32 + (hq ? 16 : 0);
            int r = ((p >> 4) + 1) * 18 + (p & 15) + 1;
            int xr = (r & 7) << 4;
            *(int4v*)(A + r * 128 + (c0 ^ xr)) = cod[tt][h2];
        }
    }
    stage_W((const unsigned char*)wq2 + (size_t)ocq * 36864, W, wid, lane);
    __syncthreads();

    // ---- conv2 ----
    #pragma unroll
    for (int e = 0; e < 16; ++e) { acc0[e] = 0; acc1[e] = 0; }
    mfma_full(A, W, pf2, h0, w0c, h1, w1c, cbase, lane, acc0, acc1);

    // ---- epilogue: out = conv2/225 + x ----
    float* ob = out + ((size_t)n * CHN + ocq * 32) * HW;
    const float* xb = x + ((size_t)n * CHN + ocq * 32) * HW;
    #pragma unroll
    for (int e = 0; e < 16; ++e) {
        int row = (e & 3) + 8 * (e >> 2) + 4 * hq;
        int idx0 = row * HW + wid * 64 + l31;
        ob[idx0]      = (float)acc0[e] * (1.f / 225.f) + xb[idx0];
        ob[idx0 + 32] = (float)acc1[e] * (1.f / 225.f) + xb[idx0 + 32];
    }
}

extern "C" void kernel_launch(void* const* d_in, const int* in_sizes, int n_in,
                              void* d_out, int out_size, void* d_ws, size_t ws_size,
                              hipStream_t stream) {
    const float* x      = (const float*)d_in[0];
    const float* gamma1 = (const float*)d_in[1];
    const float* beta1  = (const float*)d_in[2];
    const float* gamma2 = (const float*)d_in[3];
    const float* beta2  = (const float*)d_in[4];
    const float* w1     = (const float*)d_in[5];
    const float* w2     = (const float*)d_in[6];
    const float* pat1   = (const float*)d_in[7];
    const float* pat2   = (const float*)d_in[8];
    float* out = (float*)d_out;

    char* ws = (char*)d_ws;
    float* wmaxp     = (float*)(ws + 0);
    float* s1part    = (float*)(ws + 2048);
    unsigned long long* gS = (unsigned long long*)(ws + 6144);
    unsigned long long* gQ = (unsigned long long*)(ws + 14336);
    signed char* wq1 = (signed char*)(ws + 22528);
    signed char* wq2 = (signed char*)(ws + 169984);
    unsigned char* hbufT = (unsigned char*)(ws + 317440);

    k_pre1<<<656, 256, 0, stream>>>(x, w1, w2, s1part, wmaxp);
    k_mid<<<256 + 2 * 577, 256, 0, stream>>>(x, w1, w2, pat1, pat2, gamma1, beta1,
                                             s1part, wmaxp, gS, gQ, wq1, wq2, hbufT);
    k_conv1s<<<dim3(BATCH, 4), 256, 0, stream>>>(hbufT, wq1, pat1, gS, gQ);
    k_conv2<<<dim3(BATCH, 4), 256, 0, stream>>>(hbufT, wq1, wq2, pat1, pat2,
                                                gamma2, beta2, gS, gQ, x, out);
}

// Round 12
// 41.739 us; speedup vs baseline: 1.1672x; 1.0999x over previous
//
#include <hip/hip_runtime.h>
#include <math.h>

#define BATCH 128
#define CHN   128
#define HW    256            // 16*16
#define PLANE (CHN*HW)       // 32768
#define WELEM (CHN*CHN*9)    // 147456

using int4v  = __attribute__((ext_vector_type(4))) int;
using int16v = __attribute__((ext_vector_type(16))) int;
typedef unsigned int u32;

// async global->LDS, 16B per lane, dest = wave-uniform base + lane*16
__device__ __forceinline__ void gload16(const void* g, void* l) {
    __builtin_amdgcn_global_load_lds((const __attribute__((address_space(1))) u32*)g,
                                     (__attribute__((address_space(3))) u32*)l, 16, 0, 0);
}

// ---- ws layout (bytes) ----
// 0       : wmaxp (144 f)
// 2048    : s1part (512 x {sum,sumsq} = 4KB)
// 6144    : gS shadows [8][128] i64 = 8KB
// 14336   : gQ shadows [8][128] i64 = 8KB
// 22528   : wq1 i8 fragment order, 147456 B
// 169984  : wq2 i8, 147456 B
// 317440  : hbufT u8 codes1 [n][p][c0^swz(r(p))], 4 MB
// 4511744 : hbuf2 u8 codes2, 4 MB

__device__ __forceinline__ float wave_sum(float v) {
    #pragma unroll
    for (int off = 32; off; off >>= 1) v += __shfl_down(v, off, 64);
    return v;
}
__device__ __forceinline__ float wave_max(float v) {
    #pragma unroll
    for (int off = 32; off; off >>= 1) v = fmaxf(v, __shfl_down(v, off, 64));
    return v;
}

// ============ K1: stats1 partials (512 blocks) + wmax partials (144) ============
extern "C" __global__ void __launch_bounds__(256)
k_pre1(const float* __restrict__ x,
       const float* __restrict__ w1, const float* __restrict__ w2,
       float* __restrict__ s1part, float* __restrict__ wmaxp) {
    int b = blockIdx.x;
    int t = threadIdx.x;
    int lane = t & 63, wid = t >> 6;
    __shared__ float ls[8];

    if (b < 512) {
        int c = b >> 2, q = b & 3;
        const float* p = x + (size_t)(q * 32) * PLANE + c * HW + t;
        float s = 0.f, s2 = 0.f;
        #pragma unroll 8
        for (int n = 0; n < 32; ++n) {
            float v = p[n * PLANE];
            s += v; s2 += v * v;
        }
        s = wave_sum(s); s2 = wave_sum(s2);
        if (lane == 0) { ls[wid] = s; ls[4 + wid] = s2; }
        __syncthreads();
        if (t == 0) {
            s1part[b * 2]     = ls[0] + ls[1] + ls[2] + ls[3];
            s1part[b * 2 + 1] = ls[4] + ls[5] + ls[6] + ls[7];
        }
    } else {
        int i2 = b - 512;
        int y = (i2 >= 72) ? 1 : 0;
        int blk = i2 - y * 72;
        const float* w = y ? w2 : w1;
        int i = blk * 2048 + t;
        float m = 0.f;
        #pragma unroll
        for (int k = 0; k < 8; ++k)
            m = fmaxf(m, fabsf(tanhf(w[i + k * 256])));
        m = wave_max(m);
        if (lane == 0) ls[wid] = m;
        __syncthreads();
        if (t == 0)
            wmaxp[y * 72 + blk] = fmaxf(fmaxf(ls[0], ls[1]), fmaxf(ls[2], ls[3]));
    }
}

// ============ K2: actT1 (256 half-image blocks) + wquant (2x577 blocks) ============
extern "C" __global__ void __launch_bounds__(256)
k_mid(const float* __restrict__ x,
      const float* __restrict__ w1, const float* __restrict__ w2,
      const float* __restrict__ pat1, const float* __restrict__ pat2,
      const float* __restrict__ gamma1, const float* __restrict__ beta1,
      const float* __restrict__ s1part, const float* __restrict__ wmaxp,
      unsigned long long* __restrict__ gS, unsigned long long* __restrict__ gQ,
      signed char* __restrict__ wq1, signed char* __restrict__ wq2,
      unsigned char* __restrict__ hbufT) {
    int b = blockIdx.x;
    int t = threadIdx.x;

    if (b < 256) {
        // actT1: BN1 + quant + transpose, pre-swizzled codes
        __shared__ u32 tmp[32 * 129];
        __shared__ float2 tab[128];
        int n = b >> 1, half = b & 1;
        if (t < 128) {
            float S  = s1part[(4 * t) * 2]     + s1part[(4 * t + 1) * 2]
                     + s1part[(4 * t + 2) * 2] + s1part[(4 * t + 3) * 2];
            float S2 = s1part[(4 * t) * 2 + 1] + s1part[(4 * t + 1) * 2 + 1]
                     + s1part[(4 * t + 2) * 2 + 1] + s1part[(4 * t + 3) * 2 + 1];
            float mean = S * (1.f / 32768.f);
            float var  = S2 * (1.f / 32768.f) - mean * mean;
            float istd = 1.0f / sqrtf(var + 1e-5f);
            float sc = istd * gamma1[t];
            float sh = beta1[t] - mean * sc;
            tab[t] = make_float2(sc, sh);
        }
        __syncthreads();

        const float* sp = x + (size_t)n * PLANE + half * 128;
        #pragma unroll 8
        for (int j = 0; j < 16; ++j) {
            int id = j * 256 + t;            // cch = id>>5, p4 = id&31
            int cch = id >> 5, p4 = id & 31;
            float sc = tab[cch].x, sh = tab[cch].y;
            float4 v = *(const float4*)(sp + cch * HW + p4 * 4);
            unsigned q0 = (unsigned)(int)rintf(fminf(fmaxf(v.x * sc + sh, 0.f), 1.f) * 15.f);
            unsigned q1 = (unsigned)(int)rintf(fminf(fmaxf(v.y * sc + sh, 0.f), 1.f) * 15.f);
            unsigned q2 = (unsigned)(int)rintf(fminf(fmaxf(v.z * sc + sh, 0.f), 1.f) * 15.f);
            unsigned q3 = (unsigned)(int)rintf(fminf(fmaxf(v.w * sc + sh, 0.f), 1.f) * 15.f);
            tmp[p4 * 129 + cch] = q0 | (q1 << 8) | (q2 << 16) | (q3 << 24);
        }
        __syncthreads();

        unsigned char* dp = hbufT + (size_t)n * PLANE + half * 128 * CHN;
        int p4 = t >> 3;
        int c0 = (t & 7) * 16;
        u32 w[16];
        #pragma unroll
        for (int k = 0; k < 16; ++k) w[k] = tmp[p4 * 129 + c0 + k];
        #pragma unroll
        for (int pp = 0; pp < 4; ++pp) {
            int p = p4 * 4 + pp;
            int pg = half * 128 + p;
            int r = ((pg >> 4) + 1) * 18 + (pg & 15) + 1;
            int xr = (r & 7) << 4;
            int s = pp * 8;
            int4v o;
            o.x = (int)(((w[0] >> s) & 255u) | (((w[1] >> s) & 255u) << 8) |
                        (((w[2] >> s) & 255u) << 16) | (((w[3] >> s) & 255u) << 24));
            o.y = (int)(((w[4] >> s) & 255u) | (((w[5] >> s) & 255u) << 8) |
                        (((w[6] >> s) & 255u) << 16) | (((w[7] >> s) & 255u) << 24));
            o.z = (int)(((w[8] >> s) & 255u) | (((w[9] >> s) & 255u) << 8) |
                        (((w[10] >> s) & 255u) << 16) | (((w[11] >> s) & 255u) << 24));
            o.w = (int)(((w[12] >> s) & 255u) | (((w[13] >> s) & 255u) << 8) |
                        (((w[14] >> s) & 255u) << 16) | (((w[15] >> s) & 255u) << 24));
            *(int4v*)(dp + p * 128 + (c0 ^ xr)) = o;
        }
    } else {
        // weight quant: i2 in [0, 2*577)
        int i2 = b - 256;
        int y  = (i2 >= 577) ? 1 : 0;
        int xb = i2 - y * 577;

        if (xb == 576) {
            if (y == 0) {
                for (int k = t; k < 1024; k += 256) { gS[k] = 0ull; gQ[k] = 0ull; }
            }
            return;
        }
        const float* w   = y ? w2 : w1;
        const float* pat = y ? pat2 : pat1;
        signed char* wq  = y ? wq2 : wq1;

        __shared__ float lm[72];
        if (t < 72) lm[t] = wmaxp[y * 72 + t];
        __syncthreads();
        float M = lm[0];
        #pragma unroll
        for (int k = 1; k < 72; ++k) M = fmaxf(M, lm[k]);

        // byte i = ((ocq*2304 + tap*256 + q*64 + hq*32 + l31)*16 + j)
        int i = xb * 256 + t;
        int j = i & 15;
        int c = i >> 4;
        int ocq = c / 2304;
        int rem = c - ocq * 2304;
        int tap = rem >> 8;
        int r2  = rem & 255;
        int q   = r2 >> 6;
        int hq  = (r2 >> 5) & 1;
        int l31 = r2 & 31;
        int oc = ocq * 32 + l31;
        int ic = q * 32 + hq * 16 + j;
        float tv = tanhf(w[(oc * CHN + ic) * 9 + tap]);
        float tn = tv / (2.0f * M) + 0.5f;
        int mq = (int)rintf(tn * 15.f);
        mq = mq < 0 ? 0 : (mq > 15 ? 15 : mq);
        int qv = 2 * mq - 15;
        if (pat[tap] == 0.f) qv = 0;
        wq[i] = (signed char)qv;
    }
}

// ==================== shared conv helpers ====================
__device__ __forceinline__ void zero_halo(unsigned char* A, int t) {
    int4v z; z.x = 0; z.y = 0; z.z = 0; z.w = 0;
    for (int cidx = t; cidx < 544; cidx += 256) {
        int hrow = cidx >> 3, ch = cidx & 7;
        int r;
        if (hrow < 18) r = hrow;
        else if (hrow < 36) r = 306 + (hrow - 18);
        else { int h2 = hrow - 36; r = (1 + (h2 & 15)) * 18 + ((h2 >> 4) ? 17 : 0); }
        *(int4v*)(A + r * 128 + ch * 16) = z;
    }
}
__device__ __forceinline__ void stage_act(const unsigned char* ap, unsigned char* A,
                                          int wid, int lane) {
    #pragma unroll
    for (int j = 0; j < 8; ++j) {
        int p0w = j * 32 + wid * 8;
        int r0 = ((p0w >> 4) + 1) * 18 + (p0w & 15) + 1;
        gload16(ap + p0w * 128 + (lane << 4), A + r0 * 128);
    }
}
__device__ __forceinline__ void stage_W(const unsigned char* wsrc, unsigned char* W,
                                        int wid, int lane) {
    #pragma unroll
    for (int it = 0; it < 9; ++it)
        gload16(wsrc + it * 4096 + wid * 1024 + (lane << 4),
                W + it * 4096 + wid * 1024);
}
__device__ __forceinline__ void mfma_full(const unsigned char* A, const unsigned char* W,
                                          const bool pf[9],
                                          int h0, int w0c, int h1, int w1c,
                                          int cbase, int lane,
                                          int16v& acc0, int16v& acc1) {
    #pragma unroll
    for (int tap = 0; tap < 9; ++tap) {
        if (pf[tap]) {
            int dy = tap / 3, dx = tap % 3;
            int r0 = (h0 + dy) * 18 + (w0c + dx);
            int r1 = (h1 + dy) * 18 + (w1c + dx);
            int b0base = r0 * 128 + (cbase ^ ((r0 & 7) << 4));
            int b1base = r1 * 128 + (cbase ^ ((r1 & 7) << 4));
            const unsigned char* wt = W + tap * 4096 + (lane << 4);
            #pragma unroll
            for (int q = 0; q < 4; ++q) {
                int4v a0 = *(const int4v*)(wt + q * 1024);
                int4v b0 = *(const int4v*)(A + (b0base ^ (q << 5)));
                int4v b1 = *(const int4v*)(A + (b1base ^ (q << 5)));
                acc0 = __builtin_amdgcn_mfma_i32_32x32x32_i8(a0, b0, acc0, 0, 0, 0);
                acc1 = __builtin_amdgcn_mfma_i32_32x32x32_i8(a0, b1, acc1, 0, 0, 0);
            }
        }
    }
}

// ============ K3: conv1 + exact BN2 stats (XCD-local shadows), NO output write ============
extern "C" __global__ void __launch_bounds__(256, 2)
k_conv1s(const unsigned char* __restrict__ actT,
         const signed char*  __restrict__ wq,
         const float* __restrict__ pat,
         unsigned long long* __restrict__ gS, unsigned long long* __restrict__ gQ) {
    int n = blockIdx.x, ocq = blockIdx.y;
    int t = threadIdx.x;
    int lane = t & 63, wid = t >> 6;
    int l31 = lane & 31, hq = lane >> 5;

    __shared__ __align__(16) unsigned char lds[41472 + 36864];
    unsigned char* A = lds;
    unsigned char* W = lds + 41472;

    zero_halo(A, t);
    stage_W((const unsigned char*)wq + (size_t)ocq * 36864, W, wid, lane);
    stage_act(actT + (size_t)n * PLANE, A, wid, lane);

    bool pf[9];
    #pragma unroll
    for (int j = 0; j < 9; ++j) pf[j] = (pat[j] != 0.f);

    __syncthreads();

    int16v acc0, acc1;
    #pragma unroll
    for (int e = 0; e < 16; ++e) { acc0[e] = 0; acc1[e] = 0; }

    int p0 = wid * 64 + l31;
    int h0 = p0 >> 4, w0c = p0 & 15;
    int p1 = p0 + 32;
    int h1 = p1 >> 4, w1c = p1 & 15;
    int cbase = hq * 16;

    mfma_full(A, W, pf, h0, w0c, h1, w1c, cbase, lane, acc0, acc1);

    __syncthreads();      // done with LDS; reuse for stats
    int*       lsm = (int*)lds;
    long long* lq  = (long long*)(lds + 512);
    #pragma unroll
    for (int e = 0; e < 16; ++e) {
        int a0 = acc0[e], a1 = acc1[e];
        int s = a0 + a1;
        long long qq = (long long)a0 * a0 + (long long)a1 * a1;
        #pragma unroll
        for (int off = 1; off < 32; off <<= 1) {
            s  += __shfl_xor(s, off, 64);
            qq += __shfl_xor(qq, off, 64);
        }
        if (l31 == 0) {
            int ch = (e & 3) + 8 * (e >> 2) + 4 * hq;
            lsm[wid * 32 + ch] = s;
            lq [wid * 32 + ch] = qq;
        }
    }
    __syncthreads();
    if (t < 32) {
        long long S = 0, Q = 0;
        #pragma unroll
        for (int w = 0; w < 4; ++w) { S += lsm[w * 32 + t]; Q += lq[w * 32 + t]; }
        // XCD-local shadow: block (n,ocq) sits on XCD n%8 (128 % 8 == 0)
        int sh = (n & 7) * 128 + ocq * 32 + t;
        atomicAdd(gS + sh, (unsigned long long)S);
        atomicAdd(gQ + sh, (unsigned long long)Q);
    }
}

// ============ K4a: recompute conv1 (OWN 32-ch tile) -> quant -> codes2 to global ============
extern "C" __global__ void __launch_bounds__(256, 2)
k_act2(const unsigned char* __restrict__ hb,      // codes1
       const signed char* __restrict__ wq1,
       const float* __restrict__ pat1,
       const float* __restrict__ gamma2, const float* __restrict__ beta2,
       const unsigned long long* __restrict__ gS, const unsigned long long* __restrict__ gQ,
       unsigned char* __restrict__ hb2) {         // codes2 out
    int n = blockIdx.x, ocq = blockIdx.y;
    int t = threadIdx.x;
    int lane = t & 63, wid = t >> 6;
    int l31 = lane & 31, hq = lane >> 5;

    __shared__ __align__(16) unsigned char lds[41472 + 36864];
    __shared__ float2 tab[32];
    unsigned char* A = lds;
    unsigned char* W = lds + 41472;

    // BN2 scale/shift for OWN 32 channels: sum the 8 XCD shadows (exact i64)
    if (t < 32) {
        int ch = ocq * 32 + t;
        long long S = 0, Q = 0;
        #pragma unroll
        for (int r = 0; r < 8; ++r) {
            S += (long long)gS[r * 128 + ch];
            Q += (long long)gQ[r * 128 + ch];
        }
        double mean = (double)S * (1.0 / (32768.0 * 225.0));
        double ex2  = (double)Q * (1.0 / (32768.0 * 225.0 * 225.0));
        double var  = ex2 - mean * mean;
        float istd = (float)(1.0 / sqrt(var + 1e-5));
        float sc = istd * gamma2[ch];
        float sh = beta2[ch] - (float)mean * sc;
        tab[t] = make_float2(sc, sh);
    }

    zero_halo(A, t);
    stage_W((const unsigned char*)wq1 + (size_t)ocq * 36864, W, wid, lane);
    stage_act(hb + (size_t)n * PLANE, A, wid, lane);

    bool pf[9];
    #pragma unroll
    for (int j = 0; j < 9; ++j) pf[j] = (pat1[j] != 0.f);

    __syncthreads();

    int16v acc0, acc1;
    #pragma unroll
    for (int e = 0; e < 16; ++e) { acc0[e] = 0; acc1[e] = 0; }

    int p0 = wid * 64 + l31;
    int h0 = p0 >> 4, w0c = p0 & 15;
    int p1 = p0 + 32;
    int h1 = p1 >> 4, w1c = p1 & 15;
    int cbase = hq * 16;

    mfma_full(A, W, pf, h0, w0c, h1, w1c, cbase, lane, acc0, acc1);

    // quantize own accumulators -> codes2, write to global (pre-swizzled layout)
    #pragma unroll
    for (int h2 = 0; h2 < 2; ++h2) {
        const int16v& ac = h2 ? acc1 : acc0;
        int p = h2 ? p1 : p0;
        u32 wrd[4];
        #pragma unroll
        for (int k = 0; k < 4; ++k) {
            u32 pk = 0;
            #pragma unroll
            for (int e2 = 0; e2 < 4; ++e2) {
                int e = 4 * k + e2;
                int row = (e & 3) + 8 * k + 4 * hq;
                float2 ss = tab[row];
                float v = (float)ac[e] * (1.f / 225.f);
                u32 q = (u32)(int)rintf(fminf(fmaxf(v * ss.x + ss.y, 0.f), 1.f) * 15.f);
                pk |= q << (8 * e2);
            }
            wrd[k] = pk;
        }
        u32 prt[4];
        #pragma unroll
        for (int k = 0; k < 4; ++k) prt[k] = __shfl_xor(wrd[k], 32, 64);
        int4v o;
        if (hq == 0) { o.x = (int)wrd[0]; o.y = (int)prt[0]; o.z = (int)wrd[1]; o.w = (int)prt[1]; }
        else         { o.x = (int)prt[2]; o.y = (int)wrd[2]; o.z = (int)prt[3]; o.w = (int)wrd[3]; }
        int c0 = ocq * 32 + (hq ? 16 : 0);
        int r = ((p >> 4) + 1) * 18 + (p & 15) + 1;
        int xr = (r & 7) << 4;
        *(int4v*)(hb2 + (size_t)n * PLANE + p * 128 + (c0 ^ xr)) = o;
    }
}

// ============ K4b: conv2 from codes2 + residual -> out ============
extern "C" __global__ void __launch_bounds__(256, 2)
k_conv2(const unsigned char* __restrict__ hb2,    // codes2
        const signed char* __restrict__ wq2,
        const float* __restrict__ pat2,
        const float* __restrict__ x, float* __restrict__ out) {
    int n = blockIdx.x, ocq = blockIdx.y;
    int t = threadIdx.x;
    int lane = t & 63, wid = t >> 6;
    int l31 = lane & 31, hq = lane >> 5;

    __shared__ __align__(16) unsigned char lds[41472 + 36864];
    unsigned char* A = lds;
    unsigned char* W = lds + 41472;

    zero_halo(A, t);
    stage_W((const unsigned char*)wq2 + (size_t)ocq * 36864, W, wid, lane);
    stage_act(hb2 + (size_t)n * PLANE, A, wid, lane);

    bool pf[9];
    #pragma unroll
    for (int j = 0; j < 9; ++j) pf[j] = (pat2[j] != 0.f);

    __syncthreads();

    int16v acc0, acc1;
    #pragma unroll
    for (int e = 0; e < 16; ++e) { acc0[e] = 0; acc1[e] = 0; }

    int p0 = wid * 64 + l31;
    int h0 = p0 >> 4, w0c = p0 & 15;
    int p1 = p0 + 32;
    int h1 = p1 >> 4, w1c = p1 & 15;
    int cbase = hq * 16;

    mfma_full(A, W, pf, h0, w0c, h1, w1c, cbase, lane, acc0, acc1);

    float* ob = out + ((size_t)n * CHN + ocq * 32) * HW;
    const float* xb = x + ((size_t)n * CHN + ocq * 32) * HW;
    #pragma unroll
    for (int e = 0; e < 16; ++e) {
        int row = (e & 3) + 8 * (e >> 2) + 4 * hq;
        int idx0 = row * HW + wid * 64 + l31;
        ob[idx0]      = (float)acc0[e] * (1.f / 225.f) + xb[idx0];
        ob[idx0 + 32] = (float)acc1[e] * (1.f / 225.f) + xb[idx0 + 32];
    }
}

extern "C" void kernel_launch(void* const* d_in, const int* in_sizes, int n_in,
                              void* d_out, int out_size, void* d_ws, size_t ws_size,
                              hipStream_t stream) {
    const float* x      = (const float*)d_in[0];
    const float* gamma1 = (const float*)d_in[1];
    const float* beta1  = (const float*)d_in[2];
    const float* gamma2 = (const float*)d_in[3];
    const float* beta2  = (const float*)d_in[4];
    const float* w1     = (const float*)d_in[5];
    const float* w2     = (const float*)d_in[6];
    const float* pat1   = (const float*)d_in[7];
    const float* pat2   = (const float*)d_in[8];
    float* out = (float*)d_out;

    char* ws = (char*)d_ws;
    float* wmaxp     = (float*)(ws + 0);
    float* s1part    = (float*)(ws + 2048);
    unsigned long long* gS = (unsigned long long*)(ws + 6144);
    unsigned long long* gQ = (unsigned long long*)(ws + 14336);
    signed char* wq1 = (signed char*)(ws + 22528);
    signed char* wq2 = (signed char*)(ws + 169984);
    unsigned char* hbufT = (unsigned char*)(ws + 317440);
    unsigned char* hbuf2 = (unsigned char*)(ws + 4511744);

    k_pre1<<<656, 256, 0, stream>>>(x, w1, w2, s1part, wmaxp);
    k_mid<<<256 + 2 * 577, 256, 0, stream>>>(x, w1, w2, pat1, pat2, gamma1, beta1,
                                             s1part, wmaxp, gS, gQ, wq1, wq2, hbufT);
    k_conv1s<<<dim3(BATCH, 4), 256, 0, stream>>>(hbufT, wq1, pat1, gS, gQ);
    k_act2<<<dim3(BATCH, 4), 256, 0, stream>>>(hbufT, wq1, pat1, gamma2, beta2, gS, gQ, hbuf2);
    k_conv2<<<dim3(BATCH, 4), 256, 0, stream>>>(hbuf2, wq2, pat2, x, out);
}

// Round 13
// 41.442 us; speedup vs baseline: 1.1756x; 1.0072x over previous
//
#include <hip/hip_runtime.h>
#include <math.h>

#define BATCH 128
#define CHN   128
#define HW    256            // 16*16
#define PLANE (CHN*HW)       // 32768
#define WELEM (CHN*CHN*9)    // 147456

using int4v  = __attribute__((ext_vector_type(4))) int;
using int16v = __attribute__((ext_vector_type(16))) int;
typedef unsigned int u32;

// async global->LDS, 16B per lane, dest = wave-uniform base + lane*16
__device__ __forceinline__ void gload16(const void* g, void* l) {
    __builtin_amdgcn_global_load_lds((const __attribute__((address_space(1))) u32*)g,
                                     (__attribute__((address_space(3))) u32*)l, 16, 0, 0);
}

// ---- ws layout (bytes) ----
// 0       : wmaxp (144 f, max|w| partials)
// 2048    : s1part (512 x {sum,sumsq} = 4KB)
// 6144    : gS shadows [8][128] i64 = 8KB
// 14336   : gQ shadows [8][128] i64 = 8KB
// 22528   : wq1 i8 fragment order, 147456 B
// 169984  : wq2 i8, 147456 B
// 317440  : hbufT u8 codes1 [n][p][c0^swz(r(p))], 4 MB
// 4511744 : hbuf2 u8 codes2, 4 MB

__device__ __forceinline__ float wave_sum(float v) {
    #pragma unroll
    for (int off = 32; off; off >>= 1) v += __shfl_down(v, off, 64);
    return v;
}
__device__ __forceinline__ float wave_max(float v) {
    #pragma unroll
    for (int off = 32; off; off >>= 1) v = fmaxf(v, __shfl_down(v, off, 64));
    return v;
}

// ============ K1: stats1 partials (512 blocks, float4) + max|w| partials (144) ============
extern "C" __global__ void __launch_bounds__(256)
k_pre1(const float* __restrict__ x,
       const float* __restrict__ w1, const float* __restrict__ w2,
       float* __restrict__ s1part, float* __restrict__ wmaxp) {
    int b = blockIdx.x;
    int t = threadIdx.x;
    int lane = t & 63, wid = t >> 6;
    __shared__ float ls[8];

    if (b < 512) {
        int c = b >> 2, q = b & 3;
        // wave wid handles 8 images; lane covers the whole 1KB plane via float4
        const float* p = x + (size_t)(q * 32 + wid * 8) * PLANE + c * HW + lane * 4;
        float s = 0.f, s2 = 0.f;
        #pragma unroll
        for (int it = 0; it < 8; ++it) {
            float4 v = *(const float4*)(p + it * PLANE);
            s  += v.x + v.y + v.z + v.w;
            s2 += v.x * v.x + v.y * v.y + v.z * v.z + v.w * v.w;
        }
        s = wave_sum(s); s2 = wave_sum(s2);
        if (lane == 0) { ls[wid] = s; ls[4 + wid] = s2; }
        __syncthreads();
        if (t == 0) {
            s1part[b * 2]     = ls[0] + ls[1] + ls[2] + ls[3];
            s1part[b * 2 + 1] = ls[4] + ls[5] + ls[6] + ls[7];
        }
    } else {
        int i2 = b - 512;
        int y = (i2 >= 72) ? 1 : 0;
        int blk = i2 - y * 72;
        const float* w = y ? w2 : w1;
        // max|w| (tanh applied once in K2: max|tanh| == tanh(max|w|))
        const float* pw = w + blk * 2048 + t * 4;
        float4 a = *(const float4*)pw;
        float4 c4 = *(const float4*)(pw + 1024);
        float m = fmaxf(fmaxf(fmaxf(fabsf(a.x), fabsf(a.y)), fmaxf(fabsf(a.z), fabsf(a.w))),
                        fmaxf(fmaxf(fabsf(c4.x), fabsf(c4.y)), fmaxf(fabsf(c4.z), fabsf(c4.w))));
        m = wave_max(m);
        if (lane == 0) ls[wid] = m;
        __syncthreads();
        if (t == 0)
            wmaxp[y * 72 + blk] = fmaxf(fmaxf(ls[0], ls[1]), fmaxf(ls[2], ls[3]));
    }
}

// ============ K2: actT1 (256 half-image blocks) + wquant (2x145 blocks, 4 elem/thread) ============
extern "C" __global__ void __launch_bounds__(256)
k_mid(const float* __restrict__ x,
      const float* __restrict__ w1, const float* __restrict__ w2,
      const float* __restrict__ pat1, const float* __restrict__ pat2,
      const float* __restrict__ gamma1, const float* __restrict__ beta1,
      const float* __restrict__ s1part, const float* __restrict__ wmaxp,
      unsigned long long* __restrict__ gS, unsigned long long* __restrict__ gQ,
      signed char* __restrict__ wq1, signed char* __restrict__ wq2,
      unsigned char* __restrict__ hbufT) {
    int b = blockIdx.x;
    int t = threadIdx.x;

    if (b < 256) {
        // actT1: BN1 + quant + transpose, pre-swizzled codes
        __shared__ u32 tmp[32 * 129];
        __shared__ float2 tab[128];
        int n = b >> 1, half = b & 1;
        if (t < 128) {
            float S  = s1part[(4 * t) * 2]     + s1part[(4 * t + 1) * 2]
                     + s1part[(4 * t + 2) * 2] + s1part[(4 * t + 3) * 2];
            float S2 = s1part[(4 * t) * 2 + 1] + s1part[(4 * t + 1) * 2 + 1]
                     + s1part[(4 * t + 2) * 2 + 1] + s1part[(4 * t + 3) * 2 + 1];
            float mean = S * (1.f / 32768.f);
            float var  = S2 * (1.f / 32768.f) - mean * mean;
            float istd = 1.0f / sqrtf(var + 1e-5f);
            float sc = istd * gamma1[t];
            float sh = beta1[t] - mean * sc;
            tab[t] = make_float2(sc, sh);
        }
        __syncthreads();

        const float* sp = x + (size_t)n * PLANE + half * 128;
        #pragma unroll 8
        for (int j = 0; j < 16; ++j) {
            int id = j * 256 + t;            // cch = id>>5, p4 = id&31
            int cch = id >> 5, p4 = id & 31;
            float sc = tab[cch].x, sh = tab[cch].y;
            float4 v = *(const float4*)(sp + cch * HW + p4 * 4);
            unsigned q0 = (unsigned)(int)rintf(fminf(fmaxf(v.x * sc + sh, 0.f), 1.f) * 15.f);
            unsigned q1 = (unsigned)(int)rintf(fminf(fmaxf(v.y * sc + sh, 0.f), 1.f) * 15.f);
            unsigned q2 = (unsigned)(int)rintf(fminf(fmaxf(v.z * sc + sh, 0.f), 1.f) * 15.f);
            unsigned q3 = (unsigned)(int)rintf(fminf(fmaxf(v.w * sc + sh, 0.f), 1.f) * 15.f);
            tmp[p4 * 129 + cch] = q0 | (q1 << 8) | (q2 << 16) | (q3 << 24);
        }
        __syncthreads();

        unsigned char* dp = hbufT + (size_t)n * PLANE + half * 128 * CHN;
        int p4 = t >> 3;
        int c0 = (t & 7) * 16;
        u32 w[16];
        #pragma unroll
        for (int k = 0; k < 16; ++k) w[k] = tmp[p4 * 129 + c0 + k];
        #pragma unroll
        for (int pp = 0; pp < 4; ++pp) {
            int p = p4 * 4 + pp;
            int pg = half * 128 + p;
            int r = ((pg >> 4) + 1) * 18 + (pg & 15) + 1;
            int xr = (r & 7) << 4;
            int s = pp * 8;
            int4v o;
            o.x = (int)(((w[0] >> s) & 255u) | (((w[1] >> s) & 255u) << 8) |
                        (((w[2] >> s) & 255u) << 16) | (((w[3] >> s) & 255u) << 24));
            o.y = (int)(((w[4] >> s) & 255u) | (((w[5] >> s) & 255u) << 8) |
                        (((w[6] >> s) & 255u) << 16) | (((w[7] >> s) & 255u) << 24));
            o.z = (int)(((w[8] >> s) & 255u) | (((w[9] >> s) & 255u) << 8) |
                        (((w[10] >> s) & 255u) << 16) | (((w[11] >> s) & 255u) << 24));
            o.w = (int)(((w[12] >> s) & 255u) | (((w[13] >> s) & 255u) << 8) |
                        (((w[14] >> s) & 255u) << 16) | (((w[15] >> s) & 255u) << 24));
            *(int4v*)(dp + p * 128 + (c0 ^ xr)) = o;
        }
    } else {
        // weight quant: i2 in [0, 2*145); 4 elems/thread
        int i2 = b - 256;
        int y  = (i2 >= 145) ? 1 : 0;
        int xb = i2 - y * 145;

        if (xb == 144) {
            if (y == 0) {
                for (int k = t; k < 1024; k += 256) { gS[k] = 0ull; gQ[k] = 0ull; }
            }
            return;
        }
        const float* w   = y ? w2 : w1;
        const float* pat = y ? pat2 : pat1;
        signed char* wq  = y ? wq2 : wq1;

        __shared__ float lm[72];
        if (t < 72) lm[t] = wmaxp[y * 72 + t];
        __syncthreads();
        float Ma = lm[0];
        #pragma unroll
        for (int k = 1; k < 72; ++k) Ma = fmaxf(Ma, lm[k]);
        float M = tanhf(Ma);                 // max|tanh(w)| == tanh(max|w|)

        // byte i = ((ocq*2304 + tap*256 + q*64 + hq*32 + l31)*16 + j); 4 consecutive i per thread
        int i0 = (xb * 256 + t) * 4;
        int j0 = i0 & 15;
        int c = i0 >> 4;
        int ocq = c / 2304;
        int rem = c - ocq * 2304;
        int tap = rem >> 8;
        int r2  = rem & 255;
        int q   = r2 >> 6;
        int hq  = (r2 >> 5) & 1;
        int l31 = r2 & 31;
        int oc = ocq * 32 + l31;
        int icb = q * 32 + hq * 16 + j0;
        float pm = pat[tap];
        uchar4 ov;
        unsigned char* pov = (unsigned char*)&ov;
        #pragma unroll
        for (int d = 0; d < 4; ++d) {
            float tv = tanhf(w[(oc * CHN + icb + d) * 9 + tap]);
            float tn = tv / (2.0f * M) + 0.5f;
            int mq = (int)rintf(tn * 15.f);
            mq = mq < 0 ? 0 : (mq > 15 ? 15 : mq);
            int qv = 2 * mq - 15;
            if (pm == 0.f) qv = 0;
            pov[d] = (unsigned char)(signed char)qv;
        }
        *(uchar4*)(wq + i0) = ov;
    }
}

// ==================== shared conv helpers ====================
__device__ __forceinline__ void zero_halo(unsigned char* A, int t) {
    int4v z; z.x = 0; z.y = 0; z.z = 0; z.w = 0;
    for (int cidx = t; cidx < 544; cidx += 256) {
        int hrow = cidx >> 3, ch = cidx & 7;
        int r;
        if (hrow < 18) r = hrow;
        else if (hrow < 36) r = 306 + (hrow - 18);
        else { int h2 = hrow - 36; r = (1 + (h2 & 15)) * 18 + ((h2 >> 4) ? 17 : 0); }
        *(int4v*)(A + r * 128 + ch * 16) = z;
    }
}
__device__ __forceinline__ void stage_act(const unsigned char* ap, unsigned char* A,
                                          int wid, int lane) {
    #pragma unroll
    for (int j = 0; j < 8; ++j) {
        int p0w = j * 32 + wid * 8;
        int r0 = ((p0w >> 4) + 1) * 18 + (p0w & 15) + 1;
        gload16(ap + p0w * 128 + (lane << 4), A + r0 * 128);
    }
}
__device__ __forceinline__ void stage_W(const unsigned char* wsrc, unsigned char* W,
                                        int wid, int lane) {
    #pragma unroll
    for (int it = 0; it < 9; ++it)
        gload16(wsrc + it * 4096 + wid * 1024 + (lane << 4),
                W + it * 4096 + wid * 1024);
}
__device__ __forceinline__ void mfma_full(const unsigned char* A, const unsigned char* W,
                                          const bool pf[9],
                                          int h0, int w0c, int h1, int w1c,
                                          int cbase, int lane,
                                          int16v& acc0, int16v& acc1) {
    #pragma unroll
    for (int tap = 0; tap < 9; ++tap) {
        if (pf[tap]) {
            int dy = tap / 3, dx = tap % 3;
            int r0 = (h0 + dy) * 18 + (w0c + dx);
            int r1 = (h1 + dy) * 18 + (w1c + dx);
            int b0base = r0 * 128 + (cbase ^ ((r0 & 7) << 4));
            int b1base = r1 * 128 + (cbase ^ ((r1 & 7) << 4));
            const unsigned char* wt = W + tap * 4096 + (lane << 4);
            #pragma unroll
            for (int q = 0; q < 4; ++q) {
                int4v a0 = *(const int4v*)(wt + q * 1024);
                int4v b0 = *(const int4v*)(A + (b0base ^ (q << 5)));
                int4v b1 = *(const int4v*)(A + (b1base ^ (q << 5)));
                acc0 = __builtin_amdgcn_mfma_i32_32x32x32_i8(a0, b0, acc0, 0, 0, 0);
                acc1 = __builtin_amdgcn_mfma_i32_32x32x32_i8(a0, b1, acc1, 0, 0, 0);
            }
        }
    }
}

// ============ K3: conv1 + exact BN2 stats (XCD-local shadows), NO output write ============
extern "C" __global__ void __launch_bounds__(256, 2)
k_conv1s(const unsigned char* __restrict__ actT,
         const signed char*  __restrict__ wq,
         const float* __restrict__ pat,
         unsigned long long* __restrict__ gS, unsigned long long* __restrict__ gQ) {
    int n = blockIdx.x, ocq = blockIdx.y;
    int t = threadIdx.x;
    int lane = t & 63, wid = t >> 6;
    int l31 = lane & 31, hq = lane >> 5;

    __shared__ __align__(16) unsigned char lds[41472 + 36864];
    unsigned char* A = lds;
    unsigned char* W = lds + 41472;

    zero_halo(A, t);
    stage_W((const unsigned char*)wq + (size_t)ocq * 36864, W, wid, lane);
    stage_act(actT + (size_t)n * PLANE, A, wid, lane);

    bool pf[9];
    #pragma unroll
    for (int j = 0; j < 9; ++j) pf[j] = (pat[j] != 0.f);

    __syncthreads();

    int16v acc0, acc1;
    #pragma unroll
    for (int e = 0; e < 16; ++e) { acc0[e] = 0; acc1[e] = 0; }

    int p0 = wid * 64 + l31;
    int h0 = p0 >> 4, w0c = p0 & 15;
    int p1 = p0 + 32;
    int h1 = p1 >> 4, w1c = p1 & 15;
    int cbase = hq * 16;

    mfma_full(A, W, pf, h0, w0c, h1, w1c, cbase, lane, acc0, acc1);

    __syncthreads();      // done with LDS; reuse for stats
    int*       lsm = (int*)lds;
    long long* lq  = (long long*)(lds + 512);
    #pragma unroll
    for (int e = 0; e < 16; ++e) {
        int a0 = acc0[e], a1 = acc1[e];
        int s = a0 + a1;
        long long qq = (long long)a0 * a0 + (long long)a1 * a1;
        #pragma unroll
        for (int off = 1; off < 32; off <<= 1) {
            s  += __shfl_xor(s, off, 64);
            qq += __shfl_xor(qq, off, 64);
        }
        if (l31 == 0) {
            int ch = (e & 3) + 8 * (e >> 2) + 4 * hq;
            lsm[wid * 32 + ch] = s;
            lq [wid * 32 + ch] = qq;
        }
    }
    __syncthreads();
    if (t < 32) {
        long long S = 0, Q = 0;
        #pragma unroll
        for (int w = 0; w < 4; ++w) { S += lsm[w * 32 + t]; Q += lq[w * 32 + t]; }
        // XCD-local shadow: block (n,ocq) sits on XCD n%8 (128 % 8 == 0)
        int sh = (n & 7) * 128 + ocq * 32 + t;
        atomicAdd(gS + sh, (unsigned long long)S);
        atomicAdd(gQ + sh, (unsigned long long)Q);
    }
}

// ============ K4a: recompute conv1 (OWN 32-ch tile) -> quant -> codes2 to global ============
extern "C" __global__ void __launch_bounds__(256, 2)
k_act2(const unsigned char* __restrict__ hb,      // codes1
       const signed char* __restrict__ wq1,
       const float* __restrict__ pat1,
       const float* __restrict__ gamma2, const float* __restrict__ beta2,
       const unsigned long long* __restrict__ gS, const unsigned long long* __restrict__ gQ,
       unsigned char* __restrict__ hb2) {         // codes2 out
    int n = blockIdx.x, ocq = blockIdx.y;
    int t = threadIdx.x;
    int lane = t & 63, wid = t >> 6;
    int l31 = lane & 31, hq = lane >> 5;

    __shared__ __align__(16) unsigned char lds[41472 + 36864];
    __shared__ float2 tab[32];
    unsigned char* A = lds;
    unsigned char* W = lds + 41472;

    // BN2 scale/shift for OWN 32 channels: sum the 8 XCD shadows (exact i64)
    if (t < 32) {
        int ch = ocq * 32 + t;
        long long S = 0, Q = 0;
        #pragma unroll
        for (int r = 0; r < 8; ++r) {
            S += (long long)gS[r * 128 + ch];
            Q += (long long)gQ[r * 128 + ch];
        }
        double mean = (double)S * (1.0 / (32768.0 * 225.0));
        double ex2  = (double)Q * (1.0 / (32768.0 * 225.0 * 225.0));
        double var  = ex2 - mean * mean;
        float istd = (float)(1.0 / sqrt(var + 1e-5));
        float sc = istd * gamma2[ch];
        float sh = beta2[ch] - (float)mean * sc;
        tab[t] = make_float2(sc, sh);
    }

    zero_halo(A, t);
    stage_W((const unsigned char*)wq1 + (size_t)ocq * 36864, W, wid, lane);
    stage_act(hb + (size_t)n * PLANE, A, wid, lane);

    bool pf[9];
    #pragma unroll
    for (int j = 0; j < 9; ++j) pf[j] = (pat1[j] != 0.f);

    __syncthreads();

    int16v acc0, acc1;
    #pragma unroll
    for (int e = 0; e < 16; ++e) { acc0[e] = 0; acc1[e] = 0; }

    int p0 = wid * 64 + l31;
    int h0 = p0 >> 4, w0c = p0 & 15;
    int p1 = p0 + 32;
    int h1 = p1 >> 4, w1c = p1 & 15;
    int cbase = hq * 16;

    mfma_full(A, W, pf, h0, w0c, h1, w1c, cbase, lane, acc0, acc1);

    // quantize own accumulators -> codes2, write to global (pre-swizzled layout)
    #pragma unroll
    for (int h2 = 0; h2 < 2; ++h2) {
        const int16v& ac = h2 ? acc1 : acc0;
        int p = h2 ? p1 : p0;
        u32 wrd[4];
        #pragma unroll
        for (int k = 0; k < 4; ++k) {
            u32 pk = 0;
            #pragma unroll
            for (int e2 = 0; e2 < 4; ++e2) {
                int e = 4 * k + e2;
                int row = (e & 3) + 8 * k + 4 * hq;
                float2 ss = tab[row];
                float v = (float)ac[e] * (1.f / 225.f);
                u32 q = (u32)(int)rintf(fminf(fmaxf(v * ss.x + ss.y, 0.f), 1.f) * 15.f);
                pk |= q << (8 * e2);
            }
            wrd[k] = pk;
        }
        u32 prt[4];
        #pragma unroll
        for (int k = 0; k < 4; ++k) prt[k] = __shfl_xor(wrd[k], 32, 64);
        int4v o;
        if (hq == 0) { o.x = (int)wrd[0]; o.y = (int)prt[0]; o.z = (int)wrd[1]; o.w = (int)prt[1]; }
        else         { o.x = (int)prt[2]; o.y = (int)wrd[2]; o.z = (int)prt[3]; o.w = (int)wrd[3]; }
        int c0 = ocq * 32 + (hq ? 16 : 0);
        int r = ((p >> 4) + 1) * 18 + (p & 15) + 1;
        int xr = (r & 7) << 4;
        *(int4v*)(hb2 + (size_t)n * PLANE + p * 128 + (c0 ^ xr)) = o;
    }
}

// ============ K4b: conv2 from codes2 + residual -> out ============
extern "C" __global__ void __launch_bounds__(256, 2)
k_conv2(const unsigned char* __restrict__ hb2,    // codes2
        const signed char* __restrict__ wq2,
        const float* __restrict__ pat2,
        const float* __restrict__ x, float* __restrict__ out) {
    int n = blockIdx.x, ocq = blockIdx.y;
    int t = threadIdx.x;
    int lane = t & 63, wid = t >> 6;
    int l31 = lane & 31, hq = lane >> 5;

    __shared__ __align__(16) unsigned char lds[41472 + 36864];
    unsigned char* A = lds;
    unsigned char* W = lds + 41472;

    zero_halo(A, t);
    stage_W((const unsigned char*)wq2 + (size_t)ocq * 36864, W, wid, lane);
    stage_act(hb2 + (size_t)n * PLANE, A, wid, lane);

    bool pf[9];
    #pragma unroll
    for (int j = 0; j < 9; ++j) pf[j] = (pat2[j] != 0.f);

    __syncthreads();

    int16v acc0, acc1;
    #pragma unroll
    for (int e = 0; e < 16; ++e) { acc0[e] = 0; acc1[e] = 0; }

    int p0 = wid * 64 + l31;
    int h0 = p0 >> 4, w0c = p0 & 15;
    int p1 = p0 + 32;
    int h1 = p1 >> 4, w1c = p1 & 15;
    int cbase = hq * 16;

    mfma_full(A, W, pf, h0, w0c, h1, w1c, cbase, lane, acc0, acc1);

    float* ob = out + ((size_t)n * CHN + ocq * 32) * HW;
    const float* xb = x + ((size_t)n * CHN + ocq * 32) * HW;
    #pragma unroll
    for (int e = 0; e < 16; ++e) {
        int row = (e & 3) + 8 * (e >> 2) + 4 * hq;
        int idx0 = row * HW + wid * 64 + l31;
        ob[idx0]      = (float)acc0[e] * (1.f / 225.f) + xb[idx0];
        ob[idx0 + 32] = (float)acc1[e] * (1.f / 225.f) + xb[idx0 + 32];
    }
}

extern "C" void kernel_launch(void* const* d_in, const int* in_sizes, int n_in,
                              void* d_out, int out_size, void* d_ws, size_t ws_size,
                              hipStream_t stream) {
    const float* x      = (const float*)d_in[0];
    const float* gamma1 = (const float*)d_in[1];
    const float* beta1  = (const float*)d_in[2];
    const float* gamma2 = (const float*)d_in[3];
    const float* beta2  = (const float*)d_in[4];
    const float* w1     = (const float*)d_in[5];
    const float* w2     = (const float*)d_in[6];
    const float* pat1   = (const float*)d_in[7];
    const float* pat2   = (const float*)d_in[8];
    float* out = (float*)d_out;

    char* ws = (char*)d_ws;
    float* wmaxp     = (float*)(ws + 0);
    float* s1part    = (float*)(ws + 2048);
    unsigned long long* gS = (unsigned long long*)(ws + 6144);
    unsigned long long* gQ = (unsigned long long*)(ws + 14336);
    signed char* wq1 = (signed char*)(ws + 22528);
    signed char* wq2 = (signed char*)(ws + 169984);
    unsigned char* hbufT = (unsigned char*)(ws + 317440);
    unsigned char* hbuf2 = (unsigned char*)(ws + 4511744);

    k_pre1<<<656, 256, 0, stream>>>(x, w1, w2, s1part, wmaxp);
    k_mid<<<256 + 2 * 145, 256, 0, stream>>>(x, w1, w2, pat1, pat2, gamma1, beta1,
                                             s1part, wmaxp, gS, gQ, wq1, wq2, hbufT);
    k_conv1s<<<dim3(BATCH, 4), 256, 0, stream>>>(hbufT, wq1, pat1, gS, gQ);
    k_act2<<<dim3(BATCH, 4), 256, 0, stream>>>(hbufT, wq1, pat1, gamma2, beta2, gS, gQ, hbuf2);
    k_conv2<<<dim3(BATCH, 4), 256, 0, stream>>>(hbuf2, wq2, pat2, x, out);
}